// Round 7
// baseline (8248.489 us; speedup 1.0000x reference)
//
#include <hip/hip_runtime.h>
#include <hip/hip_bf16.h>
#include <hip/hip_fp16.h>

#define NNODE 16384
#define EDGES 262144
#define HOUT 64
#define TSTEPS 10
#define NKT_H 64    // padded k-tiles for h-convs (f=0..63, c=0..31 per f)
#define NKT_X 32    // padded k-tiles for x-convs (f=0..31, c=0..31 per f)

typedef __attribute__((ext_vector_type(8))) short bf16x8;
typedef __attribute__((ext_vector_type(4))) float f32x4;
typedef unsigned short u16;

__device__ __forceinline__ u16 f2b(float x) {
  __hip_bfloat16 b = __float2bfloat16(x);
  return *reinterpret_cast<const u16*>(&b);
}
__device__ __forceinline__ float b2f(u16 v) {
  union { unsigned u; float f; } c;
  c.u = ((unsigned)v) << 16;
  return c.f;
}
__device__ __forceinline__ unsigned pk2(float lo, float hi) {
  return (unsigned)f2b(lo) | ((unsigned)f2b(hi) << 16);
}

// ---------------- prep kernels ----------------

// x: (N, 32, T) f32 -> xTb: (T, N, 32) bf16
__global__ __launch_bounds__(256) void xpose_kernel(const float* __restrict__ x,
                                                    u16* __restrict__ xTb) {
  const int i = blockIdx.x * 256 + threadIdx.x;   // i = n*32 + f
  if (i >= NNODE * 32) return;
  const float* src = x + (size_t)i * TSTEPS;
  #pragma unroll
  for (int t = 0; t < TSTEPS; ++t)
    xTb[(size_t)t * NNODE * 32 + i] = f2b(src[t]);
}

__device__ __forceinline__ int cell_of(float a0, float a1, float4* b) {
  const float f0 = a0 * 4.f, f1 = a1 * 4.f;
  const float k0f = fminf(fmaxf(floorf(f0), 0.f), 3.f);
  const float k1f = fminf(fmaxf(floorf(f1), 0.f), 3.f);
  const float t0 = f0 - k0f, t1 = f1 - k1f;
  b->x = (1.f - t0) * (1.f - t1);   // (k0,   k1)
  b->y = (1.f - t0) * t1;           // (k0,   k1+1)
  b->z = t0 * (1.f - t1);           // (k0+1, k1)
  b->w = t0 * t1;                   // (k0+1, k1+1)
  return (int)k0f + 4 * (int)k1f;
}

__global__ __launch_bounds__(256) void cellcount_kernel(const int* __restrict__ ei,
                                                        const float* __restrict__ ea,
                                                        int* __restrict__ cnt) {
  const int e = blockIdx.x * 256 + threadIdx.x;
  if (e >= EDGES) return;
  const int d = ei[EDGES + e];
  float4 b;
  const int cell = cell_of(ea[2 * e], ea[2 * e + 1], &b);
  atomicAdd(&cnt[d * 16 + cell], 1);
}

__global__ __launch_bounds__(256) void nodesum_kernel(const int* __restrict__ cnt,
                                                      int* __restrict__ degi) {
  const int d = blockIdx.x * 256 + threadIdx.x;
  if (d >= NNODE) return;
  int s = 0;
  #pragma unroll
  for (int c = 0; c < 16; ++c) s += cnt[d * 16 + c];
  degi[d] = s;
}

__global__ __launch_bounds__(1024) void scan_kernel(const int* __restrict__ degi,
                                                    int* __restrict__ rp,
                                                    float* __restrict__ deg_inv) {
  __shared__ int sh[1024];
  const int tid = threadIdx.x;
  const int base = tid * 16;
  int loc[16];
  int sum = 0;
  #pragma unroll
  for (int i = 0; i < 16; ++i) { loc[i] = degi[base + i]; sum += loc[i]; }
  sh[tid] = sum;
  __syncthreads();
  for (int off = 1; off < 1024; off <<= 1) {
    int v = 0;
    if (tid >= off) v = sh[tid - off];
    __syncthreads();
    if (tid >= off) sh[tid] += v;
    __syncthreads();
  }
  int ex = sh[tid] - sum;
  #pragma unroll
  for (int i = 0; i < 16; ++i) {
    rp[base + i] = ex;
    ex += loc[i];
    deg_inv[base + i] = 1.f / (float)max(loc[i], 1);
  }
  if (tid == 1023) rp[NNODE] = ex;
}

__global__ __launch_bounds__(256) void rp2_kernel(const int* __restrict__ rp,
                                                  const int* __restrict__ cnt,
                                                  int* __restrict__ rp2) {
  const int d = blockIdx.x * 256 + threadIdx.x;
  if (d >= NNODE) return;
  int base = rp[d];
  #pragma unroll
  for (int c = 0; c < 16; ++c) {
    rp2[d * 16 + c] = base;
    base += cnt[d * 16 + c];
  }
  if (d == NNODE - 1) rp2[NNODE * 16] = base;
}

__global__ __launch_bounds__(256) void scatter2_kernel(const int* __restrict__ ei,
                                                       const float* __restrict__ ea,
                                                       const int* __restrict__ rp2,
                                                       int* __restrict__ cursor2,
                                                       int* __restrict__ esrc,
                                                       float4* __restrict__ ebasis) {
  const int e = blockIdx.x * 256 + threadIdx.x;
  if (e >= EDGES) return;
  const int s = ei[e];
  const int d = ei[EDGES + e];
  float4 b;
  const int cell = cell_of(ea[2 * e], ea[2 * e + 1], &b);
  const int pos = rp2[d * 16 + cell] + atomicAdd(&cursor2[d * 16 + cell], 1);
  esrc[pos] = s;
  ebasis[pos] = b;
}

// W + root -> padded f-major fragment layout.
// kappa = f*32 + c; tile kt = f; slot: lif = (o&15) + ((c>>3)<<4), j = c&7.
// c<25: W[(c*FIN+f)*64+o]; c==25: root[f*64+o]; c>=26: 0.
__global__ __launch_bounds__(256) void wprep_frag(const float* __restrict__ W,
                                                  const float* __restrict__ root,
                                                  u16* __restrict__ out, int fin) {
  const int i = blockIdx.x * 256 + threadIdx.x;
  if (i >= 64 * fin * 32) return;
  const int o = i / (fin * 32);
  const int rem = i % (fin * 32);
  const int f = rem >> 5, c = rem & 31;
  float v = 0.f;
  if (c < 25) v = W[(size_t)(c * fin + f) * 64 + o];
  else if (c == 25) v = root[(size_t)f * 64 + o];
  out[(((size_t)(o >> 4) * fin + f) << 9) + ((o & 15) + ((c >> 3) << 4)) * 8 + (c & 7)] =
      f2b(v);
}

// ---------------- U store: 26 values -> 4 x uint4 (dense 64B per lane) ----------------

__device__ __forceinline__ void storeU(u16* __restrict__ U, int nkt, int tile_f,
                                       int rt, int row, const float* acc, float di,
                                       unsigned raw) {
  uint4* tb = (uint4*)(U + (((size_t)rt * nkt + tile_f) << 9));
  uint4 c;
  c.x = pk2(acc[0] * di, acc[1] * di);
  c.y = pk2(acc[2] * di, acc[3] * di);
  c.z = pk2(acc[4] * di, acc[5] * di);
  c.w = pk2(acc[6] * di, acc[7] * di);
  tb[row] = c;
  c.x = pk2(acc[8] * di, acc[9] * di);
  c.y = pk2(acc[10] * di, acc[11] * di);
  c.z = pk2(acc[12] * di, acc[13] * di);
  c.w = pk2(acc[14] * di, acc[15] * di);
  tb[row + 16] = c;
  c.x = pk2(acc[16] * di, acc[17] * di);
  c.y = pk2(acc[18] * di, acc[19] * di);
  c.z = pk2(acc[20] * di, acc[21] * di);
  c.w = pk2(acc[22] * di, acc[23] * di);
  tb[row + 32] = c;
  c.x = (unsigned)f2b(acc[24] * di) | (raw << 16);
  c.y = 0; c.z = 0; c.w = 0;
  tb[row + 48] = c;
}

// ---------------- edge kernels: 2 nodes/wave, scalarized meta, interleaved ----------------

#define ITER2(ACC, BQ0, BQ1, VQ0, VQ1, SQ, EV, K0, K1)      \
  const int sN = p.esrc[EV + 3];                            \
  const float4 bN = p.ebasis[EV + 2];                       \
  const float vN = G(SQ);                                   \
  ACC[(K0) + 5 * (K1)]     += BQ0.x * VQ0;                  \
  ACC[(K0) + 5 * (K1) + 1] += BQ0.z * VQ0;                  \
  ACC[(K0) + 5 * (K1) + 5] += BQ0.y * VQ0;                  \
  ACC[(K0) + 5 * (K1) + 6] += BQ0.w * VQ0;                  \
  BQ0 = BQ1; BQ1 = bN; VQ0 = VQ1; VQ1 = vN; SQ = sN;

#define SEC2(K0, K1)                                                        \
  { const int eC = bA[(K0) + 4 * (K1) + 1];                                 \
    for (; eA < eC; ++eA) { ITER2(accA, bA0, bA1, vA0, vA1, sA2, eA, K0, K1) } } \
  { const int eC = bB[(K0) + 4 * (K1) + 1];                                 \
    for (; eB < eC; ++eB) { ITER2(accB, bB0, bB1, vB0, vB1, sB2, eB, K0, K1) } }

#define SEC2_ALL                                            \
  SEC2(0, 0) SEC2(1, 0) SEC2(2, 0) SEC2(3, 0)               \
  SEC2(0, 1) SEC2(1, 1) SEC2(2, 1) SEC2(3, 1)               \
  SEC2(0, 2) SEC2(1, 2) SEC2(2, 2) SEC2(3, 2)               \
  SEC2(0, 3) SEC2(1, 3) SEC2(2, 3) SEC2(3, 3)

#define EDGE_COMMON(DA)                                                     \
  float accA[25], accB[25];                                                 \
  _Pragma("unroll") for (int k = 0; k < 25; ++k) { accA[k] = 0.f; accB[k] = 0.f; } \
  int bA[17], bB[17];                                                       \
  _Pragma("unroll") for (int j = 0; j < 17; ++j) {                          \
    bA[j] = p.rp2[(DA) * 16 + j];                                           \
    bB[j] = p.rp2[(DA) * 16 + 16 + j];                                      \
  }                                                                         \
  int eA = bA[0], eB = bB[0];                                               \
  int sA2, sB2;                                                             \
  float4 bA0, bA1, bB0, bB1;                                                \
  float vA0, vA1, vB0, vB1;                                                 \
  { const int s0 = p.esrc[eA], s1 = p.esrc[eA + 1];                         \
    sA2 = p.esrc[eA + 2];                                                   \
    bA0 = p.ebasis[eA]; bA1 = p.ebasis[eA + 1];                             \
    vA0 = G(s0); vA1 = G(s1); }                                             \
  { const int s0 = p.esrc[eB], s1 = p.esrc[eB + 1];                         \
    sB2 = p.esrc[eB + 2];                                                   \
    bB0 = p.ebasis[eB]; bB1 = p.ebasis[eB + 1];                             \
    vB0 = G(s0); vB1 = G(s1); }                                             \
  SEC2_ALL

struct HEP {
  const u16* h_curb;
  const int* rp2;
  const int* esrc;
  const float4* ebasis;
  const float* deg_inv;
  u16* Uh;   // [1024 rt][64 kt][512 u16]
};

__global__ __launch_bounds__(256) void edge_h(HEP p) {
  const int wu = __builtin_amdgcn_readfirstlane((int)(threadIdx.x >> 6));
  const int lane = threadIdx.x & 63;
  const int dA = blockIdx.x * 8 + wu * 2;
  const int dB = dA + 1;
  #define G(S) b2f(p.h_curb[((S) << 6) + lane])
  EDGE_COMMON(dA)
  storeU(p.Uh, NKT_H, lane, dA >> 4, dA & 15, accA, p.deg_inv[dA],
         (unsigned)p.h_curb[(dA << 6) + lane]);
  storeU(p.Uh, NKT_H, lane, dB >> 4, dB & 15, accB, p.deg_inv[dB],
         (unsigned)p.h_curb[(dB << 6) + lane]);
  #undef G
}

struct XEP {
  const u16* xTb;
  const int* rp2;
  const int* esrc;
  const float4* ebasis;
  const float* deg_inv;
  u16* Ux;   // [2048 rt][32 kt][512 u16]; rt = half*1024 + (n>>4)
};

__global__ __launch_bounds__(256) void edge_x(XEP p, int tp) {
  const int wu = __builtin_amdgcn_readfirstlane((int)(threadIdx.x >> 6));
  const int lane = threadIdx.x & 63;
  const int half = lane >> 5, fl = lane & 31;
  const int dA = blockIdx.x * 8 + wu * 2;
  const int dB = dA + 1;
  const size_t xoff = (size_t)(tp * 2 + half) * NNODE * 32 + fl;
  #define G(S) b2f(p.xTb[xoff + ((size_t)(S) << 5)])
  EDGE_COMMON(dA)
  const int rtA = (half << 10) + (dA >> 4);
  storeU(p.Ux, NKT_X, fl, rtA, dA & 15, accA, p.deg_inv[dA],
         (unsigned)p.xTb[xoff + ((size_t)dA << 5)]);
  storeU(p.Ux, NKT_X, fl, rtA + ((dB >> 4) - (dA >> 4)), dB & 15, accB,
         p.deg_inv[dB], (unsigned)p.xTb[xoff + ((size_t)dB << 5)]);
  #undef G
}

// ---------------- gemm_x: U_x chunk @ Wx (W held in VGPRs) ----------------

struct XGP {
  const u16* Ux;
  const u16* Wxfrag;   // [3 gates][4 ot][32 kt][512]
  const float* b_xr; const float* b_xz; const float* b_xn;
  __half* xcr; __half* xcz; __half* xcn;
};

__global__ __launch_bounds__(768) void gemm_x(XGP p, int tp) {
  const int tid = threadIdx.x;
  const int wave = tid >> 6, lane = tid & 63;
  const int g = wave >> 2, ot = wave & 3;
  const int col = lane & 15, q = lane >> 4;
  const int o = ot * 16 + col;
  const float* bp = (g == 0) ? p.b_xr : (g == 1) ? p.b_xz : p.b_xn;
  __half* outp = (g == 0) ? p.xcr : (g == 1) ? p.xcz : p.xcn;
  const float bias = bp[o];
  bf16x8 w[NKT_X];
  const u16* wf = p.Wxfrag + (((size_t)(g * 4 + ot) * NKT_X) << 9) + lane * 8;
  #pragma unroll
  for (int kt = 0; kt < NKT_X; ++kt)
    w[kt] = *reinterpret_cast<const bf16x8*>(wf + ((size_t)kt << 9));

  for (int rl = 0; rl < 8; ++rl) {
    const int rt = blockIdx.x * 8 + rl;
    const u16* ua = p.Ux + (((size_t)rt * NKT_X) << 9) + lane * 8;
    f32x4 acc = f32x4{bias, bias, bias, bias};
    #pragma unroll
    for (int kt = 0; kt < NKT_X; ++kt) {
      const bf16x8 a = *reinterpret_cast<const bf16x8*>(ua + ((size_t)kt << 9));
      acc = __builtin_amdgcn_mfma_f32_16x16x32_bf16(a, w[kt], acc, 0, 0, 0);
    }
    const int t = tp * 2 + (rt >> 10);
    const int nbase = (rt & 1023) << 4;
    #pragma unroll
    for (int j = 0; j < 4; ++j) {
      const int n = nbase + q * 4 + j;
      outp[((size_t)t * NNODE + n) * 64 + o] = __float2half(acc[j]);
    }
  }
}

// ---------------- gemm_h + GRU (sequential step) ----------------

struct HGP {
  const u16* Uh;
  const u16* Whfrag;   // [2 gates][4 ot][64 kt][512]
  const float* b_hr; const float* b_hz;
  const float* h_cur;
  float* h_next;
  u16* h_nextb;
  const __half* xcr; const __half* xcz; const __half* xcn;
  u16* hs;
};

__global__ __launch_bounds__(512) void gemm_h(HGP p, int t) {
  __shared__ __align__(16) float4 UA4[4096];   // 65536 B; gates overlay after MFMA
  const int tid = threadIdx.x;
  const int wave = tid >> 6, lane = tid & 63;
  const int rt = blockIdx.x;
  {
    const float4* src = (const float4*)(p.Uh + (((size_t)rt * NKT_H) << 9));
    for (int i = tid; i < 4096; i += 512) UA4[i] = src[i];
  }
  __syncthreads();

  const int g = wave & 1, ot = wave >> 1;
  const int col = lane & 15, q = lane >> 4;
  const int o = ot * 16 + col;
  const float bias = g ? p.b_hz[o] : p.b_hr[o];
  f32x4 acc = f32x4{bias, bias, bias, bias};
  const u16* ua = (const u16*)UA4 + lane * 8;
  const u16* wf = p.Whfrag + (((size_t)(g * 4 + ot) * NKT_H) << 9) + lane * 8;
  #pragma unroll 4
  for (int kt = 0; kt < NKT_H; ++kt) {
    const bf16x8 a = *reinterpret_cast<const bf16x8*>(ua + ((size_t)kt << 9));
    const bf16x8 w = *reinterpret_cast<const bf16x8*>(wf + ((size_t)kt << 9));
    acc = __builtin_amdgcn_mfma_f32_16x16x32_bf16(a, w, acc, 0, 0, 0);
  }
  __syncthreads();
  float* gates = (float*)UA4;   // [2][16][64] overlay
  #pragma unroll
  for (int j = 0; j < 4; ++j)
    gates[(g << 10) + (q * 4 + j) * 64 + o] = acc[j];
  __syncthreads();

  #pragma unroll
  for (int rep = 0; rep < 2; ++rep) {
    const int i = tid + rep * 512;
    const int nloc = i >> 6, oo = i & 63;
    const int node = (rt << 4) + nloc;
    const size_t idx = (size_t)node * 64 + oo;
    const size_t tix = (size_t)t * NNODE * 64 + idx;
    const float hrv = gates[nloc * 64 + oo];
    const float hzv = gates[1024 + nloc * 64 + oo];
    const float xrv = __half2float(p.xcr[tix]);
    const float xzv = __half2float(p.xcz[tix]);
    const float xnv = __half2float(p.xcn[tix]);
    const float r = 1.f / (1.f + __expf(-(xrv + hrv)));
    const float z = 1.f / (1.f + __expf(-(xzv + hzv)));
    const float ng = 1.f - 2.f / (__expf(2.f * (xnv + r * hrv)) + 1.f);  // tanh
    const float hp = p.h_cur[idx];
    const float hn = (1.f - z) * ng + z * hp;
    p.h_next[idx] = hn;
    const u16 hb = f2b(hn);
    p.h_nextb[idx] = hb;
    p.hs[tix] = hb;
  }
}

// ---------------- finalize: hs [t][n][o] bf16 -> out (B,G,H,T) f32 ----------------

__global__ __launch_bounds__(256) void finalize_kernel(const u16* __restrict__ hs,
                                                       float* __restrict__ out,
                                                       float* __restrict__ out_last) {
  const int i = blockIdx.x * 256 + threadIdx.x;   // i = n*64 + o
  if (i >= NNODE * 64) return;
  float* ob = out + (size_t)(i >> 6) * 640 + (size_t)(i & 63) * 10;
  #pragma unroll
  for (int t = 0; t < TSTEPS; ++t)
    ob[t] = b2f(hs[(size_t)t * NNODE * 64 + i]);
  out_last[i] = b2f(hs[(size_t)9 * NNODE * 64 + i]);
}

// ---------------- host launch ----------------

extern "C" void kernel_launch(void* const* d_in, const int* in_sizes, int n_in,
                              void* d_out, int out_size, void* d_ws, size_t ws_size,
                              hipStream_t stream) {
  const float* x = (const float*)d_in[0];
  const int* ei = (const int*)d_in[1];
  const float* ea = (const float*)d_in[2];
  const float* W_xr = (const float*)d_in[3];
  const float* root_xr = (const float*)d_in[4];
  const float* b_xr = (const float*)d_in[5];
  const float* W_hr = (const float*)d_in[6];
  const float* root_hr = (const float*)d_in[7];
  const float* b_hr = (const float*)d_in[8];
  const float* W_xz = (const float*)d_in[9];
  const float* root_xz = (const float*)d_in[10];
  const float* b_xz = (const float*)d_in[11];
  const float* W_hz = (const float*)d_in[12];
  const float* root_hz = (const float*)d_in[13];
  const float* b_hz = (const float*)d_in[14];
  const float* W_xn = (const float*)d_in[15];
  const float* root_xn = (const float*)d_in[16];
  const float* b_xn = (const float*)d_in[17];

  char* w = (char*)d_ws;
  u16* xTb = (u16*)w;          w += (size_t)TSTEPS * NNODE * 32 * 2;     // 10.5 MB
  __half* xcr = (__half*)w;    w += (size_t)TSTEPS * NNODE * 64 * 2;     // 21 MB
  __half* xcz = (__half*)w;    w += (size_t)TSTEPS * NNODE * 64 * 2;     // 21 MB
  __half* xcn = (__half*)w;    w += (size_t)TSTEPS * NNODE * 64 * 2;     // 21 MB
  u16* hs = (u16*)w;           w += (size_t)TSTEPS * NNODE * 64 * 2;     // 21 MB
  float* h0 = (float*)w;       w += (size_t)NNODE * HOUT * 4;
  float* h1 = (float*)w;       w += (size_t)NNODE * HOUT * 4;
  u16* h0b = (u16*)w;          w += (size_t)NNODE * HOUT * 2;
  u16* h1b = (u16*)w;          w += (size_t)NNODE * HOUT * 2;
  float4* ebasis = (float4*)w; w += (size_t)(EDGES + 16) * 16;
  int* esrc = (int*)w;         w += (size_t)(EDGES + 16) * 4;
  u16* Whfrag = (u16*)w;       w += (size_t)2 * 4 * NKT_H * 512 * 2;     // 1 MB
  u16* Wxfrag = (u16*)w;       w += (size_t)3 * 4 * NKT_X * 512 * 2;     // 384 KB
  u16* Uh = (u16*)w;           w += (size_t)1024 * NKT_H * 512 * 2;      // 67 MB
  u16* Ux = (u16*)w;           w += (size_t)2048 * NKT_X * 512 * 2;      // 67 MB
  int* cnt = (int*)w;          w += (size_t)NNODE * 16 * 4;              // 1 MB
  int* cursor2 = (int*)w;      w += (size_t)NNODE * 16 * 4;              // 1 MB
  int* rp2 = (int*)w;          w += (size_t)(NNODE * 16 + 16) * 4;       // 1 MB
  int* degi = (int*)w;         w += (size_t)NNODE * 4;
  int* rp = (int*)w;           w += (size_t)(NNODE + 4) * 4;
  float* deg_inv = (float*)w;  w += (size_t)NNODE * 4;

  hipMemsetAsync(cnt, 0, (size_t)NNODE * 16 * 4, stream);
  hipMemsetAsync(cursor2, 0, (size_t)NNODE * 16 * 4, stream);
  hipMemsetAsync(h0, 0, (size_t)NNODE * HOUT * 4, stream);
  hipMemsetAsync(h0b, 0, (size_t)NNODE * HOUT * 2, stream);
  hipMemsetAsync((void*)(ebasis + EDGES), 0, 16 * 16, stream);
  hipMemsetAsync(esrc + EDGES, 0, 16 * 4, stream);

  xpose_kernel<<<(NNODE * 32 + 255) / 256, 256, 0, stream>>>(x, xTb);
  cellcount_kernel<<<(EDGES + 255) / 256, 256, 0, stream>>>(ei, ea, cnt);
  nodesum_kernel<<<(NNODE + 255) / 256, 256, 0, stream>>>(cnt, degi);
  scan_kernel<<<1, 1024, 0, stream>>>(degi, rp, deg_inv);
  rp2_kernel<<<(NNODE + 255) / 256, 256, 0, stream>>>(rp, cnt, rp2);
  scatter2_kernel<<<(EDGES + 255) / 256, 256, 0, stream>>>(ei, ea, rp2, cursor2,
                                                           esrc, ebasis);
  wprep_frag<<<(64 * 64 * 32 + 255) / 256, 256, 0, stream>>>(W_hr, root_hr, Whfrag, 64);
  wprep_frag<<<(64 * 64 * 32 + 255) / 256, 256, 0, stream>>>(
      W_hz, root_hz, Whfrag + (size_t)4 * NKT_H * 512, 64);
  wprep_frag<<<(64 * 32 * 32 + 255) / 256, 256, 0, stream>>>(W_xr, root_xr, Wxfrag, 32);
  wprep_frag<<<(64 * 32 * 32 + 255) / 256, 256, 0, stream>>>(
      W_xz, root_xz, Wxfrag + (size_t)4 * NKT_X * 512, 32);
  wprep_frag<<<(64 * 32 * 32 + 255) / 256, 256, 0, stream>>>(
      W_xn, root_xn, Wxfrag + (size_t)8 * NKT_X * 512, 32);

  // ---- x path: per t-pair, edge-accumulate then GEMM ----
  XEP xe;
  xe.xTb = xTb; xe.rp2 = rp2; xe.esrc = esrc; xe.ebasis = ebasis;
  xe.deg_inv = deg_inv; xe.Ux = Ux;
  XGP xg;
  xg.Ux = Ux; xg.Wxfrag = Wxfrag;
  xg.b_xr = b_xr; xg.b_xz = b_xz; xg.b_xn = b_xn;
  xg.xcr = xcr; xg.xcz = xcz; xg.xcn = xcn;
  for (int tp = 0; tp < TSTEPS / 2; ++tp) {
    edge_x<<<NNODE / 8, 256, 0, stream>>>(xe, tp);
    gemm_x<<<256, 768, 0, stream>>>(xg, tp);
  }

  // ---- h path: sequential steps ----
  HEP he;
  he.rp2 = rp2; he.esrc = esrc; he.ebasis = ebasis;
  he.deg_inv = deg_inv; he.Uh = Uh;
  HGP hg;
  hg.Uh = Uh; hg.Whfrag = Whfrag;
  hg.b_hr = b_hr; hg.b_hz = b_hz;
  hg.xcr = xcr; hg.xcz = xcz; hg.xcn = xcn;
  hg.hs = hs;

  float* ha = h0; float* hb_ = h1;
  u16* hab = h0b; u16* hbb = h1b;
  for (int t = 0; t < TSTEPS; ++t) {
    he.h_curb = hab;
    edge_h<<<NNODE / 8, 256, 0, stream>>>(he);
    hg.h_cur = ha; hg.h_next = hb_; hg.h_nextb = hbb;
    gemm_h<<<NNODE / 16, 512, 0, stream>>>(hg, t);
    float* tf = ha; ha = hb_; hb_ = tf;
    u16* tb = hab; hab = hbb; hbb = tb;
  }

  float* out = (float*)d_out;
  float* out_last = out + (size_t)NNODE * HOUT * TSTEPS;
  finalize_kernel<<<(NNODE * 64 + 255) / 256, 256, 0, stream>>>(hs, out, out_last);
}

// Round 8
// 1695.018 us; speedup vs baseline: 4.8663x; 4.8663x over previous
//
#include <hip/hip_runtime.h>
#include <hip/hip_bf16.h>
#include <hip/hip_fp16.h>

#define NNODE 16384
#define EDGES 262144
#define HOUT 64
#define TSTEPS 10
#define NKT_H 52    // (25*64 + 64)/32 k-tiles for h-convs
#define NKT_X 26    // (25*32 + 32)/32 k-tiles for x-convs

typedef __attribute__((ext_vector_type(8))) short bf16x8;
typedef __attribute__((ext_vector_type(4))) float f32x4;
typedef unsigned short u16;

__device__ __forceinline__ u16 f2b(float x) {
  __hip_bfloat16 b = __float2bfloat16(x);
  return *reinterpret_cast<const u16*>(&b);
}
__device__ __forceinline__ float b2f(u16 v) {
  union { unsigned u; float f; } c;
  c.u = ((unsigned)v) << 16;
  return c.f;
}

// ---------------- prep kernels ----------------

// x: (N, 32, T) f32 -> xTb: (T, N, 32) bf16
__global__ __launch_bounds__(256) void xpose_kernel(const float* __restrict__ x,
                                                    u16* __restrict__ xTb) {
  const int i = blockIdx.x * 256 + threadIdx.x;   // i = n*32 + f
  if (i >= NNODE * 32) return;
  const float* src = x + (size_t)i * TSTEPS;
  #pragma unroll
  for (int t = 0; t < TSTEPS; ++t)
    xTb[(size_t)t * NNODE * 32 + i] = f2b(src[t]);
}

__device__ __forceinline__ int cell_of(float a0, float a1, float4* b) {
  const float f0 = a0 * 4.f, f1 = a1 * 4.f;
  const float k0f = fminf(fmaxf(floorf(f0), 0.f), 3.f);
  const float k1f = fminf(fmaxf(floorf(f1), 0.f), 3.f);
  const float t0 = f0 - k0f, t1 = f1 - k1f;
  b->x = (1.f - t0) * (1.f - t1);   // (k0,   k1)
  b->y = (1.f - t0) * t1;           // (k0,   k1+1)
  b->z = t0 * (1.f - t1);           // (k0+1, k1)
  b->w = t0 * t1;                   // (k0+1, k1+1)
  return (int)k0f + 4 * (int)k1f;
}

__global__ __launch_bounds__(256) void cellcount_kernel(const int* __restrict__ ei,
                                                        const float* __restrict__ ea,
                                                        int* __restrict__ cnt) {
  const int e = blockIdx.x * 256 + threadIdx.x;
  if (e >= EDGES) return;
  const int d = ei[EDGES + e];
  float4 b;
  const int cell = cell_of(ea[2 * e], ea[2 * e + 1], &b);
  atomicAdd(&cnt[d * 16 + cell], 1);
}

__global__ __launch_bounds__(256) void nodesum_kernel(const int* __restrict__ cnt,
                                                      int* __restrict__ degi) {
  const int d = blockIdx.x * 256 + threadIdx.x;
  if (d >= NNODE) return;
  int s = 0;
  #pragma unroll
  for (int c = 0; c < 16; ++c) s += cnt[d * 16 + c];
  degi[d] = s;
}

__global__ __launch_bounds__(1024) void scan_kernel(const int* __restrict__ degi,
                                                    int* __restrict__ rp,
                                                    float* __restrict__ deg_inv) {
  __shared__ int sh[1024];
  const int tid = threadIdx.x;
  const int base = tid * 16;
  int loc[16];
  int sum = 0;
  #pragma unroll
  for (int i = 0; i < 16; ++i) { loc[i] = degi[base + i]; sum += loc[i]; }
  sh[tid] = sum;
  __syncthreads();
  for (int off = 1; off < 1024; off <<= 1) {
    int v = 0;
    if (tid >= off) v = sh[tid - off];
    __syncthreads();
    if (tid >= off) sh[tid] += v;
    __syncthreads();
  }
  int ex = sh[tid] - sum;
  #pragma unroll
  for (int i = 0; i < 16; ++i) {
    rp[base + i] = ex;
    ex += loc[i];
    deg_inv[base + i] = 1.f / (float)max(loc[i], 1);
  }
  if (tid == 1023) rp[NNODE] = ex;
}

__global__ __launch_bounds__(256) void rp2_kernel(const int* __restrict__ rp,
                                                  const int* __restrict__ cnt,
                                                  int* __restrict__ rp2) {
  const int d = blockIdx.x * 256 + threadIdx.x;
  if (d >= NNODE) return;
  int base = rp[d];
  #pragma unroll
  for (int c = 0; c < 16; ++c) {
    rp2[d * 16 + c] = base;
    base += cnt[d * 16 + c];
  }
  if (d == NNODE - 1) rp2[NNODE * 16] = base;
}

__global__ __launch_bounds__(256) void scatter2_kernel(const int* __restrict__ ei,
                                                       const float* __restrict__ ea,
                                                       const int* __restrict__ rp2,
                                                       int* __restrict__ cursor2,
                                                       int* __restrict__ esrc,
                                                       float4* __restrict__ ebasis) {
  const int e = blockIdx.x * 256 + threadIdx.x;
  if (e >= EDGES) return;
  const int s = ei[e];
  const int d = ei[EDGES + e];
  float4 b;
  const int cell = cell_of(ea[2 * e], ea[2 * e + 1], &b);
  const int pos = rp2[d * 16 + cell] + atomicAdd(&cursor2[d * 16 + cell], 1);
  esrc[pos] = s;
  ebasis[pos] = b;
}

// W (K x 64) + root appended -> fragment-contiguous layout:
// out[((ot*nkt + kt)<<9) + lif*8 + j], lif = (o&15) + ((k5>>3)<<4), j = k&7
__global__ __launch_bounds__(256) void wprep_frag(const float* __restrict__ W,
                                                  const float* __restrict__ root,
                                                  u16* __restrict__ out,
                                                  int kspfin, int nkt) {
  const int K = nkt * 32;
  const int i = blockIdx.x * 256 + threadIdx.x;
  if (i >= 64 * K) return;
  const int o = i / K, k = i % K;
  const float v = (k < kspfin) ? W[(size_t)k * 64 + o]
                               : root[(size_t)(k - kspfin) * 64 + o];
  const int ot = o >> 4, kt = k >> 5;
  const int lif = (o & 15) + (((k & 31) >> 3) << 4);
  out[(((size_t)(ot * nkt + kt)) << 9) + lif * 8 + (k & 7)] = f2b(v);
}

// edge-phase section macro (cell-sorted edges, compile-time tap slots)
#define SEC(K0, K1, BND)                                               \
  {                                                                    \
    const int eC = (BND);                                              \
    for (; e < eC; ++e) {                                              \
      const int sD = p.esrc[e + 3];                                    \
      const float4 b2 = p.ebasis[e + 2];                               \
      const float v2 = GATHER(sC);                                     \
      acc[(K0) + 5 * (K1)]     += b0.x * v0;                           \
      acc[(K0) + 5 * (K1) + 1] += b0.z * v0;                           \
      acc[(K0) + 5 * (K1) + 5] += b0.y * v0;                           \
      acc[(K0) + 5 * (K1) + 6] += b0.w * v0;                           \
      b0 = b1; b1 = b2; v0 = v1; v1 = v2; sC = sD;                     \
    }                                                                  \
  }

#define SEC_ALL                                                        \
  SEC(0, 0, q0.y) SEC(1, 0, q0.z) SEC(2, 0, q0.w) SEC(3, 0, q1.x)     \
  SEC(0, 1, q1.y) SEC(1, 1, q1.z) SEC(2, 1, q1.w) SEC(3, 1, q2.x)     \
  SEC(0, 2, q2.y) SEC(1, 2, q2.z) SEC(2, 2, q2.w) SEC(3, 2, q3.x)     \
  SEC(0, 3, q3.y) SEC(1, 3, q3.z) SEC(2, 3, q3.w) SEC(3, 3, eEnd)

#define SEC_PROLOGUE                                                   \
  const int4 q0 = *(const int4*)(p.rp2 + d * 16);                      \
  const int4 q1 = *(const int4*)(p.rp2 + d * 16 + 4);                  \
  const int4 q2 = *(const int4*)(p.rp2 + d * 16 + 8);                  \
  const int4 q3 = *(const int4*)(p.rp2 + d * 16 + 12);                 \
  const int eEnd = p.rp2[d * 16 + 16];                                 \
  int e = q0.x;                                                        \
  int sC;                                                              \
  float4 b0, b1;                                                       \
  float v0, v1;                                                        \
  {                                                                    \
    const int sA = p.esrc[e], sB = p.esrc[e + 1];                      \
    sC = p.esrc[e + 2];                                                \
    b0 = p.ebasis[e]; b1 = p.ebasis[e + 1];                            \
    v0 = GATHER(sA); v1 = GATHER(sB);                                  \
  }

// ---------------- edge kernels (no LDS, 1 node/wave, coalesced U store) ----------------

struct HEP {
  const u16* h_curb;
  const int* rp2;
  const int* esrc;
  const float4* ebasis;
  const float* deg_inv;
  u16* Uh;   // node-major: [node][c=0..25][f=0..63] u16
};

__global__ __launch_bounds__(256) void edge_h(HEP p) {
  const int wave = threadIdx.x >> 6, lane = threadIdx.x & 63;
  const int d = blockIdx.x * 4 + wave;
  float acc[25];
  #pragma unroll
  for (int k = 0; k < 25; ++k) acc[k] = 0.f;
  #define GATHER(S) b2f(p.h_curb[((S) << 6) + lane])
  SEC_PROLOGUE
  SEC_ALL
  #undef GATHER
  const float di = p.deg_inv[d];
  u16* un = p.Uh + (size_t)d * 1664 + lane;
  #pragma unroll
  for (int c = 0; c < 25; ++c) un[c * 64] = f2b(acc[c] * di);
  un[25 * 64] = p.h_curb[(d << 6) + lane];
}

struct XEP {
  const u16* xTb;
  const int* rp2;
  const int* esrc;
  const float4* ebasis;
  const float* deg_inv;
  u16* Ux;   // [half][node][c=0..25][f=0..31] u16
};

__global__ __launch_bounds__(256) void edge_x(XEP p, int tp) {
  const int wave = threadIdx.x >> 6, lane = threadIdx.x & 63;
  const int half = lane >> 5, fl = lane & 31;
  const int d = blockIdx.x * 4 + wave;
  const u16* __restrict__ xb = p.xTb + (size_t)(tp * 2 + half) * NNODE * 32;
  float acc[25];
  #pragma unroll
  for (int k = 0; k < 25; ++k) acc[k] = 0.f;
  #define GATHER(S) b2f(xb[((S) << 5) + fl])
  SEC_PROLOGUE
  SEC_ALL
  #undef GATHER
  const float di = p.deg_inv[d];
  u16* un = p.Ux + (size_t)half * ((size_t)NNODE * 832) + (size_t)d * 832 + fl;
  #pragma unroll
  for (int c = 0; c < 25; ++c) un[c * 32] = f2b(acc[c] * di);
  un[25 * 32] = xb[(d << 5) + fl];
}

// ---------------- gemm_x: stage rt tile to LDS fragments, W in VGPRs ----------------

struct XGP {
  const u16* Ux;
  const u16* Wxfrag;   // [3 gates][4 ot][26 kt][512]
  const float* b_xr; const float* b_xz; const float* b_xn;
  __half* xcr; __half* xcz; __half* xcn;
};

__global__ __launch_bounds__(768) void gemm_x(XGP p, int tp) {
  __shared__ __align__(16) float4 UX4[1664];   // 26624 B
  const int tid = threadIdx.x;
  const int wave = tid >> 6, lane = tid & 63;
  const int g = wave >> 2, ot = wave & 3;
  const int col = lane & 15, q = lane >> 4;
  const int o = ot * 16 + col;
  const float* bp = (g == 0) ? p.b_xr : (g == 1) ? p.b_xz : p.b_xn;
  __half* outp = (g == 0) ? p.xcr : (g == 1) ? p.xcz : p.xcn;
  const float bias = bp[o];
  bf16x8 w[NKT_X];
  const u16* wf = p.Wxfrag + (((size_t)(g * 4 + ot) * NKT_X) << 9) + lane * 8;
  #pragma unroll
  for (int kt = 0; kt < NKT_X; ++kt)
    w[kt] = *reinterpret_cast<const bf16x8*>(wf + ((size_t)kt << 9));

  for (int rl = 0; rl < 8; ++rl) {
    const int rt = blockIdx.x * 8 + rl;
    __syncthreads();
    {
      const float4* src = (const float4*)(
          p.Ux + ((size_t)(rt >> 10) * NNODE + (size_t)((rt & 1023) << 4)) * 832);
      for (int i = tid; i < 1664; i += 768) {
        const float4 v = src[i];
        const int node = i / 104;
        const int r = i - node * 104;
        const int c = r >> 2, g8 = r & 3;
        UX4[c * 64 + ((node + (g8 << 4)) ^ (c & 7))] = v;
      }
    }
    __syncthreads();
    f32x4 acc = f32x4{bias, bias, bias, bias};
    const u16* ua = (const u16*)UX4;
    #pragma unroll 2
    for (int kt = 0; kt < NKT_X; ++kt) {
      const bf16x8 a = *reinterpret_cast<const bf16x8*>(
          ua + (kt * 64 + (lane ^ (kt & 7))) * 8);
      acc = __builtin_amdgcn_mfma_f32_16x16x32_bf16(a, w[kt], acc, 0, 0, 0);
    }
    const int t = tp * 2 + (rt >> 10);
    const int nbase = (rt & 1023) << 4;
    #pragma unroll
    for (int j = 0; j < 4; ++j) {
      const int n = nbase + q * 4 + j;
      outp[((size_t)t * NNODE + n) * 64 + o] = __float2half(acc[j]);
    }
  }
}

// ---------------- gemm_h + GRU (sequential step) ----------------

struct HGP {
  const u16* Uh;
  const u16* Whfrag;   // [2 gates][4 ot][52 kt][512]
  const float* b_hr; const float* b_hz;
  const float* h_cur;
  float* h_next;
  u16* h_nextb;
  const __half* xcr; const __half* xcz; const __half* xcn;
  u16* hs;
};

__global__ __launch_bounds__(512) void gemm_h(HGP p, int t) {
  __shared__ __align__(16) float4 UA4[3328];   // 53248 B; gates overlay after MFMA
  const int tid = threadIdx.x;
  const int wave = tid >> 6, lane = tid & 63;
  const int rt = blockIdx.x;
  {
    const float4* src = (const float4*)(p.Uh + (size_t)rt * 26624);
    for (int i = tid; i < 3328; i += 512) {
      const float4 v = src[i];
      const int node = i / 208;
      const int r = i - node * 208;
      const int c = r >> 3, g8 = r & 7;
      const int kt = 2 * c + (g8 >> 2);
      const int lif = node + ((g8 & 3) << 4);
      UA4[kt * 64 + (lif ^ ((kt >> 1) & 7))] = v;
    }
  }
  __syncthreads();

  const int g = wave & 1, ot = wave >> 1;
  const int col = lane & 15, q = lane >> 4;
  const int o = ot * 16 + col;
  const float bias = g ? p.b_hz[o] : p.b_hr[o];
  f32x4 acc = f32x4{bias, bias, bias, bias};
  const u16* ua = (const u16*)UA4;
  const u16* wf = p.Whfrag + (((size_t)(g * 4 + ot) * NKT_H) << 9) + lane * 8;
  #pragma unroll 4
  for (int kt = 0; kt < NKT_H; ++kt) {
    const bf16x8 a = *reinterpret_cast<const bf16x8*>(
        ua + (kt * 64 + (lane ^ ((kt >> 1) & 7))) * 8);
    const bf16x8 w = *reinterpret_cast<const bf16x8*>(wf + ((size_t)kt << 9));
    acc = __builtin_amdgcn_mfma_f32_16x16x32_bf16(a, w, acc, 0, 0, 0);
  }
  __syncthreads();
  float* gates = (float*)UA4;   // [2][16][64] overlay
  #pragma unroll
  for (int j = 0; j < 4; ++j)
    gates[(g << 10) + (q * 4 + j) * 64 + o] = acc[j];
  __syncthreads();

  #pragma unroll
  for (int rep = 0; rep < 2; ++rep) {
    const int i = tid + rep * 512;
    const int nloc = i >> 6, oo = i & 63;
    const int node = (rt << 4) + nloc;
    const size_t idx = (size_t)node * 64 + oo;
    const size_t tix = (size_t)t * NNODE * 64 + idx;
    const float hrv = gates[nloc * 64 + oo];
    const float hzv = gates[1024 + nloc * 64 + oo];
    const float xrv = __half2float(p.xcr[tix]);
    const float xzv = __half2float(p.xcz[tix]);
    const float xnv = __half2float(p.xcn[tix]);
    const float r = 1.f / (1.f + __expf(-(xrv + hrv)));
    const float z = 1.f / (1.f + __expf(-(xzv + hzv)));
    const float ng = 1.f - 2.f / (__expf(2.f * (xnv + r * hrv)) + 1.f);  // tanh
    const float hp = p.h_cur[idx];
    const float hn = (1.f - z) * ng + z * hp;
    p.h_next[idx] = hn;
    const u16 hb = f2b(hn);
    p.h_nextb[idx] = hb;
    p.hs[tix] = hb;
  }
}

// ---------------- finalize: hs [t][n][o] bf16 -> out (B,G,H,T) f32 ----------------

__global__ __launch_bounds__(256) void finalize_kernel(const u16* __restrict__ hs,
                                                       float* __restrict__ out,
                                                       float* __restrict__ out_last) {
  const int i = blockIdx.x * 256 + threadIdx.x;   // i = n*64 + o
  if (i >= NNODE * 64) return;
  float* ob = out + (size_t)(i >> 6) * 640 + (size_t)(i & 63) * 10;
  #pragma unroll
  for (int t = 0; t < TSTEPS; ++t)
    ob[t] = b2f(hs[(size_t)t * NNODE * 64 + i]);
  out_last[i] = b2f(hs[(size_t)9 * NNODE * 64 + i]);
}

// ---------------- host launch ----------------

extern "C" void kernel_launch(void* const* d_in, const int* in_sizes, int n_in,
                              void* d_out, int out_size, void* d_ws, size_t ws_size,
                              hipStream_t stream) {
  const float* x = (const float*)d_in[0];
  const int* ei = (const int*)d_in[1];
  const float* ea = (const float*)d_in[2];
  const float* W_xr = (const float*)d_in[3];
  const float* root_xr = (const float*)d_in[4];
  const float* b_xr = (const float*)d_in[5];
  const float* W_hr = (const float*)d_in[6];
  const float* root_hr = (const float*)d_in[7];
  const float* b_hr = (const float*)d_in[8];
  const float* W_xz = (const float*)d_in[9];
  const float* root_xz = (const float*)d_in[10];
  const float* b_xz = (const float*)d_in[11];
  const float* W_hz = (const float*)d_in[12];
  const float* root_hz = (const float*)d_in[13];
  const float* b_hz = (const float*)d_in[14];
  const float* W_xn = (const float*)d_in[15];
  const float* root_xn = (const float*)d_in[16];
  const float* b_xn = (const float*)d_in[17];

  char* w = (char*)d_ws;
  u16* xTb = (u16*)w;          w += (size_t)TSTEPS * NNODE * 32 * 2;     // 10.5 MB
  __half* xcr = (__half*)w;    w += (size_t)TSTEPS * NNODE * 64 * 2;     // 21 MB
  __half* xcz = (__half*)w;    w += (size_t)TSTEPS * NNODE * 64 * 2;     // 21 MB
  __half* xcn = (__half*)w;    w += (size_t)TSTEPS * NNODE * 64 * 2;     // 21 MB
  u16* hs = (u16*)w;           w += (size_t)TSTEPS * NNODE * 64 * 2;     // 21 MB
  float* h0 = (float*)w;       w += (size_t)NNODE * HOUT * 4;
  float* h1 = (float*)w;       w += (size_t)NNODE * HOUT * 4;
  u16* h0b = (u16*)w;          w += (size_t)NNODE * HOUT * 2;
  u16* h1b = (u16*)w;          w += (size_t)NNODE * HOUT * 2;
  float4* ebasis = (float4*)w; w += (size_t)(EDGES + 16) * 16;
  int* esrc = (int*)w;         w += (size_t)(EDGES + 16) * 4;
  u16* Whfrag = (u16*)w;       w += (size_t)2 * 4 * NKT_H * 512 * 2;     // 425 KB
  u16* Wxfrag = (u16*)w;       w += (size_t)3 * 4 * NKT_X * 512 * 2;     // 319 KB
  u16* Uh = (u16*)w;           w += (size_t)NNODE * 1664 * 2;            // 54.5 MB
  u16* Ux = (u16*)w;           w += (size_t)2 * NNODE * 832 * 2;         // 54.5 MB
  int* cnt = (int*)w;          w += (size_t)NNODE * 16 * 4;              // 1 MB
  int* cursor2 = (int*)w;      w += (size_t)NNODE * 16 * 4;              // 1 MB
  int* rp2 = (int*)w;          w += (size_t)(NNODE * 16 + 16) * 4;       // 1 MB
  int* degi = (int*)w;         w += (size_t)NNODE * 4;
  int* rp = (int*)w;           w += (size_t)(NNODE + 4) * 4;
  float* deg_inv = (float*)w;  w += (size_t)NNODE * 4;

  hipMemsetAsync(cnt, 0, (size_t)NNODE * 16 * 4, stream);
  hipMemsetAsync(cursor2, 0, (size_t)NNODE * 16 * 4, stream);
  hipMemsetAsync(h0, 0, (size_t)NNODE * HOUT * 4, stream);
  hipMemsetAsync(h0b, 0, (size_t)NNODE * HOUT * 2, stream);
  hipMemsetAsync((void*)(ebasis + EDGES), 0, 16 * 16, stream);
  hipMemsetAsync(esrc + EDGES, 0, 16 * 4, stream);

  xpose_kernel<<<(NNODE * 32 + 255) / 256, 256, 0, stream>>>(x, xTb);
  cellcount_kernel<<<(EDGES + 255) / 256, 256, 0, stream>>>(ei, ea, cnt);
  nodesum_kernel<<<(NNODE + 255) / 256, 256, 0, stream>>>(cnt, degi);
  scan_kernel<<<1, 1024, 0, stream>>>(degi, rp, deg_inv);
  rp2_kernel<<<(NNODE + 255) / 256, 256, 0, stream>>>(rp, cnt, rp2);
  scatter2_kernel<<<(EDGES + 255) / 256, 256, 0, stream>>>(ei, ea, rp2, cursor2,
                                                           esrc, ebasis);
  const int gWH = (64 * NKT_H * 32 + 255) / 256;
  const int gWX = (64 * NKT_X * 32 + 255) / 256;
  wprep_frag<<<gWH, 256, 0, stream>>>(W_hr, root_hr, Whfrag, 1600, NKT_H);
  wprep_frag<<<gWH, 256, 0, stream>>>(W_hz, root_hz, Whfrag + (size_t)4 * NKT_H * 512, 1600, NKT_H);
  wprep_frag<<<gWX, 256, 0, stream>>>(W_xr, root_xr, Wxfrag, 800, NKT_X);
  wprep_frag<<<gWX, 256, 0, stream>>>(W_xz, root_xz, Wxfrag + (size_t)4 * NKT_X * 512, 800, NKT_X);
  wprep_frag<<<gWX, 256, 0, stream>>>(W_xn, root_xn, Wxfrag + (size_t)8 * NKT_X * 512, 800, NKT_X);

  // ---- x path: per t-pair, edge-accumulate then GEMM ----
  XEP xe;
  xe.xTb = xTb; xe.rp2 = rp2; xe.esrc = esrc; xe.ebasis = ebasis;
  xe.deg_inv = deg_inv; xe.Ux = Ux;
  XGP xg;
  xg.Ux = Ux; xg.Wxfrag = Wxfrag;
  xg.b_xr = b_xr; xg.b_xz = b_xz; xg.b_xn = b_xn;
  xg.xcr = xcr; xg.xcz = xcz; xg.xcn = xcn;
  for (int tp = 0; tp < TSTEPS / 2; ++tp) {
    edge_x<<<NNODE / 4, 256, 0, stream>>>(xe, tp);
    gemm_x<<<256, 768, 0, stream>>>(xg, tp);
  }

  // ---- h path: sequential steps ----
  HEP he;
  he.rp2 = rp2; he.esrc = esrc; he.ebasis = ebasis;
  he.deg_inv = deg_inv; he.Uh = Uh;
  HGP hg;
  hg.Uh = Uh; hg.Whfrag = Whfrag;
  hg.b_hr = b_hr; hg.b_hz = b_hz;
  hg.xcr = xcr; hg.xcz = xcz; hg.xcn = xcn;
  hg.hs = hs;

  float* ha = h0; float* hb_ = h1;
  u16* hab = h0b; u16* hbb = h1b;
  for (int t = 0; t < TSTEPS; ++t) {
    he.h_curb = hab;
    edge_h<<<NNODE / 4, 256, 0, stream>>>(he);
    hg.h_cur = ha; hg.h_next = hb_; hg.h_nextb = hbb;
    gemm_h<<<NNODE / 16, 512, 0, stream>>>(hg, t);
    float* tf = ha; ha = hb_; hb_ = tf;
    u16* tb = hab; hab = hbb; hbb = tb;
  }

  float* out = (float*)d_out;
  float* out_last = out + (size_t)NNODE * HOUT * TSTEPS;
  finalize_kernel<<<(NNODE * 64 + 255) / 256, 256, 0, stream>>>(hs, out, out_last);
}